// Round 8
// baseline (259.529 us; speedup 1.0000x reference)
//
#include <hip/hip_runtime.h>

#define NN 100000
#define NE 1250000
#define HD 64
#define BMW 3125         // bitmap words = NN/32
#define GRID 1024
#define TPB 256
#define NTH (GRID * TPB)     // 262144 threads
#define NWAVE (NTH / 64)     // 4096 waves
#define S_N2CAP 128

#define CAP_L3   4096
#define CAP_L2   65536
#define CAP_L1   262144
#define CAP_NL2  4096
#define CAP_NL1  65536

// ctrl: 0=cntL3 1=cntL2 2=cntL1 3=cntNL2 4=cntNL1
// Discipline: read-only inputs (src/dst/z/zt/weights/pair) -> plain cached
// loads. Cross-phase mutable data -> device-scope relaxed atomics (LLC-
// coherent, no cache-maintenance instructions).

__device__ __forceinline__ unsigned ldg_u(const unsigned* p) {
    return __hip_atomic_load(p, __ATOMIC_RELAXED, __HIP_MEMORY_SCOPE_AGENT);
}
__device__ __forceinline__ int ldg_i(const int* p) {
    return __hip_atomic_load(p, __ATOMIC_RELAXED, __HIP_MEMORY_SCOPE_AGENT);
}
__device__ __forceinline__ float ldg_f(const float* p) {
    return __hip_atomic_load(p, __ATOMIC_RELAXED, __HIP_MEMORY_SCOPE_AGENT);
}
__device__ __forceinline__ void stg_u(unsigned* p, unsigned v) {
    __hip_atomic_store(p, v, __ATOMIC_RELAXED, __HIP_MEMORY_SCOPE_AGENT);
}
__device__ __forceinline__ void stg_i(int* p, int v) {
    __hip_atomic_store(p, v, __ATOMIC_RELAXED, __HIP_MEMORY_SCOPE_AGENT);
}
__device__ __forceinline__ void stg_f(float* p, float v) {
    __hip_atomic_store(p, v, __ATOMIC_RELAXED, __HIP_MEMORY_SCOPE_AGENT);
}

// Fence-free grid barrier: __syncthreads drains vmcnt (stg/atomics reached
// LLC) before arrival; relaxed add + relaxed spin; 16 slots x 64B.
__device__ __forceinline__ void gbar(unsigned* cnt16, unsigned target) {
    __syncthreads();
    if (threadIdx.x == 0) {
        __hip_atomic_fetch_add(&cnt16[(blockIdx.x & 15u) * 16], 1u,
                               __ATOMIC_RELAXED, __HIP_MEMORY_SCOPE_AGENT);
        long guard = 0;
        for (;;) {
            unsigned s = 0;
#pragma unroll
            for (int i = 0; i < 16; ++i)
                s += __hip_atomic_load(&cnt16[i * 16], __ATOMIC_RELAXED,
                                       __HIP_MEMORY_SCOPE_AGENT);
            if (s >= target) break;
            __builtin_amdgcn_s_sleep(1);
            if (++guard > (1L << 22)) break;   // deadlock escape
        }
        asm volatile("" ::: "memory");
    }
    __syncthreads();
}

// Zero barrier counters + ctrl before the persistent kernel (cannot be done
// race-free inside it). Kernel boundary provides the release.
__global__ void k_pre(unsigned* cnt16, int* ctrl, float* cnt_in,
                      const int* __restrict__ pair) {
    int i = threadIdx.x;   // 256 threads
    cnt16[i] = 0u;
    if (i < 16) ctrl[i] = 0;
    if (i == 0) { cnt_in[pair[0]] = 0.f; cnt_in[pair[1]] = 0.f; }
}

__global__ __launch_bounds__(TPB, 4) void k_all(
        const int* __restrict__ z, const int* __restrict__ src,
        const int* __restrict__ dst, const int* __restrict__ pair,
        const float* __restrict__ zt,
        const float* __restrict__ W1, const float* __restrict__ b1,
        const float* __restrict__ W2, const float* __restrict__ b2,
        const float* __restrict__ W3, const float* __restrict__ b3,
        const float* __restrict__ l1w, const float* __restrict__ l1b,
        const float* __restrict__ l2w, const float* __restrict__ l2b,
        float* out,
        float* bufA, float* bufB, float* cnt_out, float* cnt_in,
        unsigned* B0, unsigned* B1, unsigned* B2,
        int* L3, int* L2, int* L1, int* NL2, int* NL1,
        int* ctrl, unsigned* cnt16) {
    // 34.3 KB shared: bm aliases the x2 region (bm dead before P8 uses x2s)
    __shared__ float smem[S_N2CAP * HD + 4 * HD];
    __shared__ int   s_nl2[S_N2CAP];
    __shared__ int   cnts[8];
    unsigned* bm = (unsigned*)smem;
    const int tid  = threadIdx.x;
    const int gtid = blockIdx.x * TPB + tid;
    const int gw   = gtid >> 6, lane = gtid & 63;
    const int wv   = tid >> 6,  ln   = tid & 63;   // 4 local waves
    const int p0 = pair[0], p1 = pair[1];

    // ---- P0: zero bitmaps (to LLC) ----
    for (int i = gtid; i < 3 * BMW; i += NTH) {
        if (i < BMW)           stg_u(&B0[i], 0u);
        else if (i < 2 * BMW)  stg_u(&B1[i - BMW], 0u);
        else                   stg_u(&B2[i - 2 * BMW], 0u);
    }
    gbar(cnt16, 1u * GRID);

    // ---- P1: scan3 — edges into {pair}; mark NL2 in B2, lazy-zero counters ----
    for (int t = gtid; t < NE / 4; t += NTH) {
        int4 d4 = ((const int4*)dst)[t];
#pragma unroll
        for (int k = 0; k < 4; ++k) {
            int d = (k == 0) ? d4.x : (k == 1) ? d4.y : (k == 2) ? d4.z : d4.w;
            if (d == p0 || d == p1) {
                int e = t * 4 + k, s = src[e];
                int idx = atomicAdd(&ctrl[0], 1);
                if (idx < CAP_L3) stg_i(&L3[idx], e);
                unsigned m = 1u << (s & 31);
                unsigned old = atomicOr(&B2[s >> 5], m);
                if (!(old & m)) {
                    stg_f(&cnt_out[s], 0.f); stg_f(&cnt_in[s], 0.f);
                    int j = atomicAdd(&ctrl[3], 1);
                    if (j < CAP_NL2) stg_i(&NL2[j], s);
                }
            }
        }
    }
    gbar(cnt16, 2u * GRID);

    // ---- P2: scan2 — dst in B2 (LDS-staged); mark NL1 in B1 ----
    for (int i = tid; i < BMW; i += TPB) bm[i] = ldg_u(&B2[i]);
    __syncthreads();
    for (int t = gtid; t < NE / 4; t += NTH) {
        int4 d4 = ((const int4*)dst)[t];
#pragma unroll
        for (int k = 0; k < 4; ++k) {
            int d = (k == 0) ? d4.x : (k == 1) ? d4.y : (k == 2) ? d4.z : d4.w;
            if ((bm[d >> 5] >> (d & 31)) & 1u) {
                int e = t * 4 + k, s = src[e];
                int idx = atomicAdd(&ctrl[1], 1);
                if (idx < CAP_L2) stg_i(&L2[idx], e);
                unsigned m = 1u << (s & 31);
                unsigned old = atomicOr(&B1[s >> 5], m);
                if (!(old & m)) {
                    stg_f(&cnt_out[s], 0.f); stg_f(&cnt_in[s], 0.f);
                    int j = atomicAdd(&ctrl[4], 1);
                    if (j < CAP_NL1) stg_i(&NL1[j], s);
                }
            }
        }
    }
    gbar(cnt16, 3u * GRID);

    // ---- P3: scan1 — dst in B1; set B0 (no list), lazy-zero cnt_out ----
    for (int i = tid; i < BMW; i += TPB) bm[i] = ldg_u(&B1[i]);
    __syncthreads();
    for (int t = gtid; t < NE / 4; t += NTH) {
        int4 d4 = ((const int4*)dst)[t];
#pragma unroll
        for (int k = 0; k < 4; ++k) {
            int d = (k == 0) ? d4.x : (k == 1) ? d4.y : (k == 2) ? d4.z : d4.w;
            if ((bm[d >> 5] >> (d & 31)) & 1u) {
                int e = t * 4 + k, s = src[e];
                int idx = atomicAdd(&ctrl[2], 1);
                if (idx < CAP_L1) stg_i(&L1[idx], e);
                unsigned m = 1u << (s & 31);
                unsigned old = atomicOr(&B0[s >> 5], m);
                if (!(old & m)) stg_f(&cnt_out[s], 0.f);
            }
        }
    }
    gbar(cnt16, 4u * GRID);

    // ---- P4: out-deg (union bitmap), deduped in-deg, agg1-zero ----
    for (int i = tid; i < BMW; i += TPB)
        bm[i] = ldg_u(&B0[i]) | ldg_u(&B1[i]) | ldg_u(&B2[i]);
    if (tid < 6) cnts[tid] = ldg_i(&ctrl[tid]);
    __syncthreads();
    const int e3 = min(cnts[0], CAP_L3), e2 = min(cnts[1], CAP_L2);
    const int e1 = min(cnts[2], CAP_L1);
    const int n2 = min(cnts[3], CAP_NL2), n1 = min(cnts[4], CAP_NL1);
    for (int t = gtid; t < NE / 4; t += NTH) {
        int4 s4 = ((const int4*)src)[t];
#pragma unroll
        for (int k = 0; k < 4; ++k) {
            int s = (k == 0) ? s4.x : (k == 1) ? s4.y : (k == 2) ? s4.z : s4.w;
            if ((bm[s >> 5] >> (s & 31)) & 1u) atomicAdd(&cnt_out[s], 1.0f);
        }
    }
    // in-degree from edge lists, dedup priority B1 > B2 > pair
    for (int t = gtid; t < e1 + e2 + e3; t += NTH) {
        int e, which;
        if (t < e1)            { e = ldg_i(&L1[t]);           which = 1; }
        else if (t < e1 + e2)  { e = ldg_i(&L2[t - e1]);      which = 2; }
        else                   { e = ldg_i(&L3[t - e1 - e2]); which = 3; }
        int d = dst[e];
        bool inB1 = (ldg_u(&B1[d >> 5]) >> (d & 31)) & 1u;
        bool count;
        if (which == 1)      count = true;
        else if (which == 2) count = !inB1;
        else                 count = !inB1 && !((ldg_u(&B2[d >> 5]) >> (d & 31)) & 1u);
        if (count) atomicAdd(&cnt_in[d], 1.0f);
    }
    // zero agg1 rows (NL1) in bufB
    for (int r = gw; r < n1; r += NWAVE)
        stg_f(&bufB[ldg_i(&NL1[r]) * HD + lane], 0.0f);
    gbar(cnt16, 5u * GRID);

    // ---- P5: scatter1 — agg1[d] += w0(s) * zt[z[s]] (x0 fused) ----
    for (int r = gw; r < e1; r += NWAVE) {
        int e = ldg_i(&L1[r]), s = src[e], d = dst[e];
        float w0 = 1.0f / sqrtf(fmaxf(ldg_f(&cnt_out[s]), 1.0f));
        atomicAdd(&bufB[d * HD + lane], w0 * zt[z[s] * HD + lane]);
    }
    gbar(cnt16, 6u * GRID);

    // ---- P6: gemm1 (x1 = relu((agg1*nin)@W1+b1)) + zero agg2 rows (NL2) ----
    for (int r = gw; r < n1 + n2; r += NWAVE) {
        if (r < n1) {
            int v = ldg_i(&NL1[r]);
            float nin = 1.0f / sqrtf(fmaxf(ldg_f(&cnt_in[v]), 1.0f));
            float a = ldg_f(&bufB[v * HD + lane]) * nin;
            float acc = b1[lane];
#pragma unroll
            for (int i = 0; i < HD; ++i)
                acc += __shfl(a, i, 64) * W1[i * HD + lane];
            stg_f(&bufB[v * HD + lane], fmaxf(acc, 0.0f));
        } else {
            stg_f(&bufA[ldg_i(&NL2[r - n1]) * HD + lane], 0.0f);
        }
    }
    gbar(cnt16, 7u * GRID);

    // ---- P7: scatter2 — agg2[d] += w0(s) * x1[s] ----
    for (int r = gw; r < e2; r += NWAVE) {
        int e = ldg_i(&L2[r]), s = src[e], d = dst[e];
        float w0 = 1.0f / sqrtf(fmaxf(ldg_f(&cnt_out[s]), 1.0f));
        atomicAdd(&bufA[d * HD + lane], w0 * ldg_f(&bufB[s * HD + lane]));
    }
    gbar(cnt16, 8u * GRID);

    // ---- P8 (block 0): gemm2 in LDS, scatter3, gemm3, final MLP ----
    if (blockIdx.x != 0) return;
    float* x2s = smem;                       // reuses bm region (dead)
    float* xs  = smem + S_N2CAP * HD;
    float* xf  = smem + S_N2CAP * HD + 2 * HD;
    const int n2c = min(n2, S_N2CAP);
    if (tid < n2c) s_nl2[tid] = ldg_i(&NL2[tid]);
    if (tid < 2 * HD) xs[tid] = 0.0f;
    __syncthreads();
    for (int r = wv; r < n2c; r += TPB / 64) {    // gemm2: x2 = relu(...)
        int v = s_nl2[r];
        float nin = 1.0f / sqrtf(fmaxf(ldg_f(&cnt_in[v]), 1.0f));
        float a = ldg_f(&bufA[v * HD + ln]) * nin;
        float acc = b2[ln];
#pragma unroll
        for (int i = 0; i < HD; ++i)
            acc += __shfl(a, i, 64) * W2[i * HD + ln];
        x2s[r * HD + ln] = fmaxf(acc, 0.0f);
    }
    __syncthreads();
    for (int r = wv; r < e3; r += TPB / 64) {     // scatter3 into xs
        int e = ldg_i(&L3[r]), s = src[e], d = dst[e];
        float w0 = 1.0f / sqrtf(fmaxf(ldg_f(&cnt_out[s]), 1.0f));
        int slot = -1;
        for (int j = 0; j < n2c; ++j) if (s_nl2[j] == s) { slot = j; break; }
        if (slot >= 0) {
            float c = w0 * x2s[slot * HD + ln];
            if (d == p0)             atomicAdd(&xs[ln], c);
            if (d == p1 && p1 != p0) atomicAdd(&xs[HD + ln], c);
        }
    }
    __syncthreads();
    if (tid < 128) {                              // gemm3 (no relu)
        int w2 = tid >> 6, l2_ = tid & 63;
        int pv = w2 ? p1 : p0;
        int rs = (w2 && p1 != p0) ? 1 : 0;        // p0==p1: both use row 0
        float nin = 1.0f / sqrtf(fmaxf(ldg_f(&cnt_in[pv]), 1.0f));
        float a = xs[rs * HD + l2_] * nin;
        float acc = b3[l2_];
#pragma unroll
        for (int i = 0; i < HD; ++i)
            acc += __shfl(a, i, 64) * W3[i * HD + l2_];
        xf[w2 * HD + l2_] = acc;
    }
    __syncthreads();
    if (tid < 64) {                               // final MLP
        float h = xf[tid] * xf[HD + tid];
        float t2 = l1b[tid];
#pragma unroll
        for (int i = 0; i < HD; ++i)
            t2 += __shfl(h, i, 64) * l1w[i * HD + tid];
        t2 = fmaxf(t2, 0.0f);
        float val = t2 * l2w[tid];
#pragma unroll
        for (int off = 32; off; off >>= 1)
            val += __shfl_down(val, off, 64);
        if (tid == 0) out[0] = val + l2b[0];
    }
}

extern "C" void kernel_launch(void* const* d_in, const int* in_sizes, int n_in,
                              void* d_out, int out_size, void* d_ws, size_t ws_size,
                              hipStream_t stream) {
    const int*   z    = (const int*)d_in[0];
    const int*   src  = (const int*)d_in[1];
    const int*   dst  = (const int*)d_in[2];
    const int*   pair = (const int*)d_in[3];
    const float* zt   = (const float*)d_in[4];
    const float* W1   = (const float*)d_in[5];
    const float* b1   = (const float*)d_in[6];
    const float* W2   = (const float*)d_in[7];
    const float* b2   = (const float*)d_in[8];
    const float* W3   = (const float*)d_in[9];
    const float* b3   = (const float*)d_in[10];
    const float* l1w  = (const float*)d_in[11];
    const float* l1b  = (const float*)d_in[12];
    const float* l2w  = (const float*)d_in[13];
    const float* l2b  = (const float*)d_in[14];
    float* out = (float*)d_out;

    char* w = (char*)d_ws;
    auto alloc = [&](size_t bytes) {
        char* p = w;
        w += (bytes + 255) & ~(size_t)255;
        return p;
    };
    float*    bufA    = (float*)alloc((size_t)NN * HD * 4);
    float*    bufB    = (float*)alloc((size_t)NN * HD * 4);
    float*    cnt_out = (float*)alloc((size_t)NN * 4);
    float*    cnt_in  = (float*)alloc((size_t)NN * 4);
    unsigned* B0      = (unsigned*)alloc((size_t)BMW * 4);
    unsigned* B1      = (unsigned*)alloc((size_t)BMW * 4);
    unsigned* B2      = (unsigned*)alloc((size_t)BMW * 4);
    int*      L3      = (int*)alloc((size_t)CAP_L3 * 4);
    int*      L2      = (int*)alloc((size_t)CAP_L2 * 4);
    int*      L1      = (int*)alloc((size_t)CAP_L1 * 4);
    int*      NL2     = (int*)alloc((size_t)CAP_NL2 * 4);
    int*      NL1     = (int*)alloc((size_t)CAP_NL1 * 4);
    int*      ctrl    = (int*)alloc(256);
    unsigned* cnt16   = (unsigned*)alloc(1024);

    k_pre<<<1, 256, 0, stream>>>(cnt16, ctrl, cnt_in, pair);
    k_all<<<GRID, TPB, 0, stream>>>(z, src, dst, pair, zt,
                                    W1, b1, W2, b2, W3, b3,
                                    l1w, l1b, l2w, l2b, out,
                                    bufA, bufB, cnt_out, cnt_in,
                                    B0, B1, B2, L3, L2, L1, NL2, NL1,
                                    ctrl, cnt16);
}

// Round 9
// 221.992 us; speedup vs baseline: 1.1691x; 1.1691x over previous
//
#include <hip/hip_runtime.h>

#define NN 100000
#define NE 1250000
#define HD 64
#define BMW 3125            // bitmap words = NN/32
#define HALF4 156250        // (NE/4)/2 int4 elements per half
#define NBS 611             // ceil(HALF4/256) sweep blocks

#define CAP_L3   4096
#define CAP_L2   65536
#define CAP_L1   262144
#define CAP_NL2  4096
#define CAP_NL1  65536
#define S_N2CAP  128

// ctrl: 0=cntL3 1=cntL2 2=cntL1 3=cntNL2 4=cntNL1
// B2 = NL2 (in-nbrs of pair), B1 = NL1, B0 = NL0 then UNION (seeded in scan1).
// Cross-kernel visibility comes from kernel boundaries; no fences needed.

__global__ void k_init(unsigned* B0, unsigned* B1, unsigned* B2,
                       int* ctrl, float* cnt_in, const int* __restrict__ pair) {
    int i = blockIdx.x * blockDim.x + threadIdx.x;
    for (int t = i; t < 3 * BMW; t += gridDim.x * blockDim.x) {
        if (t < BMW)           B0[t] = 0u;
        else if (t < 2 * BMW)  B1[t - BMW] = 0u;
        else                   B2[t - 2 * BMW] = 0u;
    }
    if (i < 16) ctrl[i] = 0;
    if (i == 0) { cnt_in[pair[0]] = 0.f; cnt_in[pair[1]] = 0.f; }
}

// sweep: edges into {pair}; mark srcs in B2, append NL2, lazy-zero counters
__global__ __launch_bounds__(256) void k_scan3(
        const int* __restrict__ src, const int* __restrict__ dst,
        const int* __restrict__ pair, unsigned* B2,
        float* cnt_out, float* cnt_in, int* L3, int* NL2, int* ctrl) {
    int t = blockIdx.x * blockDim.x + threadIdx.x;
    if (t >= HALF4) return;
    int p0 = pair[0], p1 = pair[1];
    int4 a = ((const int4*)dst)[t];            // two independent loads up front
    int4 b = ((const int4*)dst)[t + HALF4];
#pragma unroll
    for (int h = 0; h < 2; ++h) {
        int4 d4 = h ? b : a;
        int base = (h ? (t + HALF4) : t) * 4;
#pragma unroll
        for (int k = 0; k < 4; ++k) {
            int d = (k == 0) ? d4.x : (k == 1) ? d4.y : (k == 2) ? d4.z : d4.w;
            if (d == p0 || d == p1) {
                int e = base + k, s = src[e];
                int idx = atomicAdd(&ctrl[0], 1);
                if (idx < CAP_L3) L3[idx] = e;
                unsigned m = 1u << (s & 31);
                unsigned old = atomicOr(&B2[s >> 5], m);
                if (!(old & m)) {
                    cnt_out[s] = 0.f; cnt_in[s] = 0.f;
                    int j = atomicAdd(&ctrl[3], 1);
                    if (j < CAP_NL2) NL2[j] = s;
                }
            }
        }
    }
}

// sweep: dst-bit in B2 -> collect L2, set B1/NL1, lazy-zero
__global__ __launch_bounds__(256) void k_scan2(
        const int* __restrict__ src, const int* __restrict__ dst,
        const unsigned* __restrict__ B2, unsigned* B1,
        float* cnt_out, float* cnt_in, int* L2, int* NL1, int* ctrl) {
    int t = blockIdx.x * blockDim.x + threadIdx.x;
    if (t >= HALF4) return;
    int4 a = ((const int4*)dst)[t];
    int4 b = ((const int4*)dst)[t + HALF4];
#pragma unroll
    for (int h = 0; h < 2; ++h) {
        int4 d4 = h ? b : a;
        int base = (h ? (t + HALF4) : t) * 4;
#pragma unroll
        for (int k = 0; k < 4; ++k) {
            int d = (k == 0) ? d4.x : (k == 1) ? d4.y : (k == 2) ? d4.z : d4.w;
            if ((B2[d >> 5] >> (d & 31)) & 1u) {
                int e = base + k, s = src[e];
                int idx = atomicAdd(&ctrl[1], 1);
                if (idx < CAP_L2) L2[idx] = e;
                unsigned m = 1u << (s & 31);
                unsigned old = atomicOr(&B1[s >> 5], m);
                if (!(old & m)) {
                    cnt_out[s] = 0.f; cnt_in[s] = 0.f;
                    int j = atomicAdd(&ctrl[4], 1);
                    if (j < CAP_NL1) NL1[j] = s;
                }
            }
        }
    }
}

// sweep: dst-bit in B1 -> collect L1, set B0, lazy-zero cnt_out.
// Prologue seeds B0 |= B1|B2 via atomicOr so B0 ends as the UNION.
// Race-safety: if a sweep hit's first-set beats the seed for that word, the
// node was already lazily zeroed by scan2/scan3 (if in B1|B2) or is a true
// first-set; re-zeroing before any increment is idempotent.
__global__ __launch_bounds__(256) void k_scan1(
        const int* __restrict__ src, const int* __restrict__ dst,
        const unsigned* __restrict__ B1s, const unsigned* __restrict__ B2,
        unsigned* B0, unsigned* B1m,
        float* cnt_out, int* L1, int* ctrl) {
    int t = blockIdx.x * blockDim.x + threadIdx.x;
    for (int i = t; i < BMW; i += NBS * 256) {
        unsigned u = B1s[i] | B2[i];
        if (u) atomicOr(&B0[i], u);
    }
    if (t >= HALF4) return;
    int4 a = ((const int4*)dst)[t];
    int4 b = ((const int4*)dst)[t + HALF4];
#pragma unroll
    for (int h = 0; h < 2; ++h) {
        int4 d4 = h ? b : a;
        int base = (h ? (t + HALF4) : t) * 4;
#pragma unroll
        for (int k = 0; k < 4; ++k) {
            int d = (k == 0) ? d4.x : (k == 1) ? d4.y : (k == 2) ? d4.z : d4.w;
            if ((B1s[d >> 5] >> (d & 31)) & 1u) {
                int e = base + k, s = src[e];
                int idx = atomicAdd(&ctrl[2], 1);
                if (idx < CAP_L1) L1[idx] = e;
                unsigned m = 1u << (s & 31);
                unsigned old = atomicOr(&B0[s >> 5], m);
                if (!(old & m)) cnt_out[s] = 0.f;
            }
        }
    }
}

// fused: [0,NBS) out-deg sweep over union B0 | [NBS,+32) deduped in-deg |
//        [NBS+32,+32) zero agg1 rows (NL1) in bufB
__global__ __launch_bounds__(256) void k_mid(
        const int* __restrict__ src, const int* __restrict__ dst,
        const unsigned* __restrict__ B0, const unsigned* __restrict__ B1,
        const unsigned* __restrict__ B2,
        float* cnt_out, float* cnt_in, float* bufB,
        const int* __restrict__ L3, const int* __restrict__ L2,
        const int* __restrict__ L1, const int* __restrict__ NL1,
        const int* __restrict__ ctrl) {
    int blk = blockIdx.x, tid = threadIdx.x;
    if (blk < NBS) {
        int t = blk * 256 + tid;
        if (t >= HALF4) return;
        int4 a = ((const int4*)src)[t];
        int4 b = ((const int4*)src)[t + HALF4];
#pragma unroll
        for (int h = 0; h < 2; ++h) {
            int4 s4 = h ? b : a;
#pragma unroll
            for (int k = 0; k < 4; ++k) {
                int s = (k == 0) ? s4.x : (k == 1) ? s4.y : (k == 2) ? s4.z : s4.w;
                if ((B0[s >> 5] >> (s & 31)) & 1u) atomicAdd(&cnt_out[s], 1.0f);
            }
        }
    } else if (blk < NBS + 32) {
        int e3 = min(ctrl[0], CAP_L3), e2 = min(ctrl[1], CAP_L2), e1 = min(ctrl[2], CAP_L1);
        for (int t = (blk - NBS) * 256 + tid; t < e1 + e2 + e3; t += 32 * 256) {
            int e, which;
            if (t < e1)            { e = L1[t];           which = 1; }
            else if (t < e1 + e2)  { e = L2[t - e1];      which = 2; }
            else                   { e = L3[t - e1 - e2]; which = 3; }
            int d = dst[e];
            bool inB1 = (B1[d >> 5] >> (d & 31)) & 1u;
            bool count;
            if (which == 1)      count = true;
            else if (which == 2) count = !inB1;
            else                 count = !inB1 && !((B2[d >> 5] >> (d & 31)) & 1u);
            if (count) atomicAdd(&cnt_in[d], 1.0f);
        }
    } else {
        int n1 = min(ctrl[4], CAP_NL1);
        float4 zz = make_float4(0.f, 0.f, 0.f, 0.f);
        for (int t = (blk - NBS - 32) * 256 + tid; t < n1 * 16; t += 32 * 256) {
            int v = NL1[t >> 4], c = (t & 15) * 4;
            *(float4*)&bufB[v * HD + c] = zz;
        }
    }
}

// scatter1: agg1[d] += w0(s) * zt[z[s]]  (x0 fused, wave per edge)
__global__ __launch_bounds__(256) void k_scatter1(
        const int* __restrict__ L1, const int* __restrict__ ctrl,
        const int* __restrict__ src, const int* __restrict__ dst,
        const int* __restrict__ z, const float* __restrict__ zt,
        const float* __restrict__ cnt_out, float* bufB) {
    int e1 = min(ctrl[2], CAP_L1);
    int gtid = blockIdx.x * blockDim.x + threadIdx.x;
    int gw = gtid >> 6, lane = gtid & 63;
    int nw = (gridDim.x * blockDim.x) >> 6;
    for (int r = gw; r < e1; r += nw) {
        int e = L1[r], s = src[e], d = dst[e];
        float w0 = 1.0f / sqrtf(fmaxf(cnt_out[s], 1.0f));
        atomicAdd(&bufB[d * HD + lane], w0 * zt[z[s] * HD + lane]);
    }
}

// one block, 1024 threads: gemm1, scatter2(LDS agg2), gemm2(LDS), scatter3,
// gemm3, final MLP. Weights staged through a 16KB LDS buffer per phase.
__global__ __launch_bounds__(1024) void k_tail(
        const int* __restrict__ src, const int* __restrict__ dst,
        const int* __restrict__ pair,
        const float* __restrict__ W1, const float* __restrict__ b1,
        const float* __restrict__ W2, const float* __restrict__ b2,
        const float* __restrict__ W3, const float* __restrict__ b3,
        const float* __restrict__ l1w, const float* __restrict__ l1b,
        const float* __restrict__ l2w, const float* __restrict__ l2b,
        float* out, float* bufB,
        const float* __restrict__ cnt_out, const float* __restrict__ cnt_in,
        const int* __restrict__ L3, const int* __restrict__ L2,
        const int* __restrict__ NL2, const int* __restrict__ NL1,
        const int* __restrict__ ctrl) {
    __shared__ float wbuf[HD * HD];          // 16 KB staged weights
    __shared__ float x2agg[S_N2CAP * HD];    // 32 KB agg2/x2 slots
    __shared__ int   s_nl2[S_N2CAP];
    __shared__ float xs[2 * HD], xf[2 * HD];
    __shared__ int   cnts[8];
    const int tid = threadIdx.x;
    const int wv = tid >> 6, ln = tid & 63;  // 16 waves
    const int p0 = pair[0], p1 = pair[1];

    if (tid < 5) cnts[tid] = ctrl[tid];
    __syncthreads();
    const int e3 = min(cnts[0], CAP_L3), e2 = min(cnts[1], CAP_L2);
    const int n2 = min(cnts[3], S_N2CAP), n1 = min(cnts[4], CAP_NL1);

    for (int i = tid; i < HD * HD; i += 1024) wbuf[i] = W1[i];
    for (int i = tid; i < S_N2CAP * HD; i += 1024) x2agg[i] = 0.0f;
    if (tid < n2) s_nl2[tid] = NL2[tid];
    if (tid < 2 * HD) xs[tid] = 0.0f;
    __syncthreads();

    // gemm1: x1 = relu((agg1*nin) @ W1 + b1), in-place in bufB
    for (int r = wv; r < n1; r += 16) {
        int v = NL1[r];
        float nin = 1.0f / sqrtf(fmaxf(cnt_in[v], 1.0f));
        float aa = bufB[v * HD + ln] * nin;
        float acc = b1[ln];
#pragma unroll
        for (int i = 0; i < HD; ++i)
            acc += __shfl(aa, i, 64) * wbuf[i * HD + ln];
        bufB[v * HD + ln] = fmaxf(acc, 0.0f);
    }
    __syncthreads();

    // scatter2: agg2[slot(d)] += w0(s) * x1[s], wave per edge
    for (int r = wv; r < e2; r += 16) {
        int e = L2[r], s = src[e], d = dst[e];
        float w0 = 1.0f / sqrtf(fmaxf(cnt_out[s], 1.0f));
        int slot = 0;
        for (int j = 0; j < n2; ++j) if (s_nl2[j] == d) { slot = j; break; }
        atomicAdd(&x2agg[slot * HD + ln], w0 * bufB[s * HD + ln]);
    }
    __syncthreads();
    for (int i = tid; i < HD * HD; i += 1024) wbuf[i] = W2[i];
    __syncthreads();

    // gemm2 in LDS: x2 = relu((agg2*nin) @ W2 + b2)
    for (int r = wv; r < n2; r += 16) {
        int v = s_nl2[r];
        float nin = 1.0f / sqrtf(fmaxf(cnt_in[v], 1.0f));
        float aa = x2agg[r * HD + ln] * nin;
        float acc = b2[ln];
#pragma unroll
        for (int i = 0; i < HD; ++i)
            acc += __shfl(aa, i, 64) * wbuf[i * HD + ln];
        x2agg[r * HD + ln] = fmaxf(acc, 0.0f);
    }
    __syncthreads();

    // scatter3: xs rows {p0,p1} += w0(s) * x2[slot(s)]
    for (int r = wv; r < e3; r += 16) {
        int e = L3[r], s = src[e], d = dst[e];
        float w0 = 1.0f / sqrtf(fmaxf(cnt_out[s], 1.0f));
        int slot = 0;
        for (int j = 0; j < n2; ++j) if (s_nl2[j] == s) { slot = j; break; }
        float c = w0 * x2agg[slot * HD + ln];
        if (d == p0)             atomicAdd(&xs[ln], c);
        if (d == p1 && p1 != p0) atomicAdd(&xs[HD + ln], c);
    }
    __syncthreads();
    for (int i = tid; i < HD * HD; i += 1024) wbuf[i] = W3[i];
    __syncthreads();

    // gemm3 (no relu) on the two pair rows
    if (tid < 128) {
        int pv = wv ? p1 : p0;
        int rs = (wv && p1 != p0) ? 1 : 0;       // p0==p1: both use row 0
        float nin = 1.0f / sqrtf(fmaxf(cnt_in[pv], 1.0f));
        float aa = xs[rs * HD + ln] * nin;
        float acc = b3[ln];
#pragma unroll
        for (int i = 0; i < HD; ++i)
            acc += __shfl(aa, i, 64) * wbuf[i * HD + ln];
        xf[wv * HD + ln] = acc;
    }
    __syncthreads();
    for (int i = tid; i < HD * HD; i += 1024) wbuf[i] = l1w[i];
    __syncthreads();

    // final MLP
    if (tid < 64) {
        float h = xf[tid] * xf[HD + tid];
        float t2 = l1b[tid];
#pragma unroll
        for (int i = 0; i < HD; ++i)
            t2 += __shfl(h, i, 64) * wbuf[i * HD + tid];
        t2 = fmaxf(t2, 0.0f);
        float val = t2 * l2w[tid];
#pragma unroll
        for (int off = 32; off; off >>= 1)
            val += __shfl_down(val, off, 64);
        if (tid == 0) out[0] = val + l2b[0];
    }
}

extern "C" void kernel_launch(void* const* d_in, const int* in_sizes, int n_in,
                              void* d_out, int out_size, void* d_ws, size_t ws_size,
                              hipStream_t stream) {
    const int*   z    = (const int*)d_in[0];
    const int*   src  = (const int*)d_in[1];
    const int*   dst  = (const int*)d_in[2];
    const int*   pair = (const int*)d_in[3];
    const float* zt   = (const float*)d_in[4];
    const float* W1   = (const float*)d_in[5];
    const float* b1   = (const float*)d_in[6];
    const float* W2   = (const float*)d_in[7];
    const float* b2   = (const float*)d_in[8];
    const float* W3   = (const float*)d_in[9];
    const float* b3   = (const float*)d_in[10];
    const float* l1w  = (const float*)d_in[11];
    const float* l1b  = (const float*)d_in[12];
    const float* l2w  = (const float*)d_in[13];
    const float* l2b  = (const float*)d_in[14];
    float* out = (float*)d_out;

    char* w = (char*)d_ws;
    auto alloc = [&](size_t bytes) {
        char* p = w;
        w += (bytes + 255) & ~(size_t)255;
        return p;
    };
    float*    bufB    = (float*)alloc((size_t)NN * HD * 4);
    float*    cnt_out = (float*)alloc((size_t)NN * 4);
    float*    cnt_in  = (float*)alloc((size_t)NN * 4);
    unsigned* B0      = (unsigned*)alloc((size_t)BMW * 4);
    unsigned* B1      = (unsigned*)alloc((size_t)BMW * 4);
    unsigned* B2      = (unsigned*)alloc((size_t)BMW * 4);
    int*      L3      = (int*)alloc((size_t)CAP_L3 * 4);
    int*      L2      = (int*)alloc((size_t)CAP_L2 * 4);
    int*      L1      = (int*)alloc((size_t)CAP_L1 * 4);
    int*      NL2     = (int*)alloc((size_t)CAP_NL2 * 4);
    int*      NL1     = (int*)alloc((size_t)CAP_NL1 * 4);
    int*      ctrl    = (int*)alloc(256);

    dim3 b(256);

    k_init<<<40, b, 0, stream>>>(B0, B1, B2, ctrl, cnt_in, pair);
    k_scan3<<<NBS, b, 0, stream>>>(src, dst, pair, B2, cnt_out, cnt_in, L3, NL2, ctrl);
    k_scan2<<<NBS, b, 0, stream>>>(src, dst, B2, B1, cnt_out, cnt_in, L2, NL1, ctrl);
    k_scan1<<<NBS, b, 0, stream>>>(src, dst, B1, B2, B0, B1, cnt_out, L1, ctrl);
    k_mid<<<NBS + 64, b, 0, stream>>>(src, dst, B0, B1, B2, cnt_out, cnt_in,
                                      bufB, L3, L2, L1, NL1, ctrl);
    k_scatter1<<<512, b, 0, stream>>>(L1, ctrl, src, dst, z, zt, cnt_out, bufB);
    k_tail<<<1, 1024, 0, stream>>>(src, dst, pair, W1, b1, W2, b2, W3, b3,
                                   l1w, l1b, l2w, l2b, out, bufB,
                                   cnt_out, cnt_in, L3, L2, NL2, NL1, ctrl);
}

// Round 10
// 175.452 us; speedup vs baseline: 1.4792x; 1.2653x over previous
//
#include <hip/hip_runtime.h>

#define NN 100000
#define NE 1250000
#define HD 64
#define BMW 3125            // bitmap words = NN/32
#define HALF4 156250        // (NE/4)/2 int4 elements per half
#define NBS 611             // ceil(HALF4/256) sweep blocks

#define CAP_L3   4096
#define CAP_L2   65536
#define CAP_L1   262144
#define CAP_NL2  4096
#define CAP_NL1  65536
#define S_N2CAP  128

// ctrl: 0=cntL3 1=cntL2 2=cntL1 3=cntNL2 4=cntNL1
// B2 = NL2 (in-nbrs of pair), B1 = NL1, B0 = NL0 then UNION (seeded in scan1).
// Cross-kernel visibility via kernel boundaries; no fences needed.

__global__ void k_init(unsigned* B0, unsigned* B1, unsigned* B2,
                       int* ctrl, float* cnt_in, const int* __restrict__ pair) {
    int i = blockIdx.x * blockDim.x + threadIdx.x;
    for (int t = i; t < 3 * BMW; t += gridDim.x * blockDim.x) {
        if (t < BMW)           B0[t] = 0u;
        else if (t < 2 * BMW)  B1[t - BMW] = 0u;
        else                   B2[t - 2 * BMW] = 0u;
    }
    if (i < 16) ctrl[i] = 0;
    if (i == 0) { cnt_in[pair[0]] = 0.f; cnt_in[pair[1]] = 0.f; }
}

// sweep: edges into {pair}; mark srcs in B2, append NL2, lazy-zero counters
__global__ __launch_bounds__(256) void k_scan3(
        const int* __restrict__ src, const int* __restrict__ dst,
        const int* __restrict__ pair, unsigned* B2,
        float* cnt_out, float* cnt_in, int* L3, int* NL2, int* ctrl) {
    int t = blockIdx.x * blockDim.x + threadIdx.x;
    if (t >= HALF4) return;
    int p0 = pair[0], p1 = pair[1];
    int4 a = ((const int4*)dst)[t];            // two independent loads up front
    int4 b = ((const int4*)dst)[t + HALF4];
#pragma unroll
    for (int h = 0; h < 2; ++h) {
        int4 d4 = h ? b : a;
        int base = (h ? (t + HALF4) : t) * 4;
#pragma unroll
        for (int k = 0; k < 4; ++k) {
            int d = (k == 0) ? d4.x : (k == 1) ? d4.y : (k == 2) ? d4.z : d4.w;
            if (d == p0 || d == p1) {
                int e = base + k, s = src[e];
                int idx = atomicAdd(&ctrl[0], 1);
                if (idx < CAP_L3) L3[idx] = e;
                unsigned m = 1u << (s & 31);
                unsigned old = atomicOr(&B2[s >> 5], m);
                if (!(old & m)) {
                    cnt_out[s] = 0.f; cnt_in[s] = 0.f;
                    int j = atomicAdd(&ctrl[3], 1);
                    if (j < CAP_NL2) NL2[j] = s;
                }
            }
        }
    }
}

// sweep: dst-bit in B2 -> collect L2, set B1/NL1, lazy-zero
__global__ __launch_bounds__(256) void k_scan2(
        const int* __restrict__ src, const int* __restrict__ dst,
        const unsigned* __restrict__ B2, unsigned* B1,
        float* cnt_out, float* cnt_in, int* L2, int* NL1, int* ctrl) {
    int t = blockIdx.x * blockDim.x + threadIdx.x;
    if (t >= HALF4) return;
    int4 a = ((const int4*)dst)[t];
    int4 b = ((const int4*)dst)[t + HALF4];
#pragma unroll
    for (int h = 0; h < 2; ++h) {
        int4 d4 = h ? b : a;
        int base = (h ? (t + HALF4) : t) * 4;
#pragma unroll
        for (int k = 0; k < 4; ++k) {
            int d = (k == 0) ? d4.x : (k == 1) ? d4.y : (k == 2) ? d4.z : d4.w;
            if ((B2[d >> 5] >> (d & 31)) & 1u) {
                int e = base + k, s = src[e];
                int idx = atomicAdd(&ctrl[1], 1);
                if (idx < CAP_L2) L2[idx] = e;
                unsigned m = 1u << (s & 31);
                unsigned old = atomicOr(&B1[s >> 5], m);
                if (!(old & m)) {
                    cnt_out[s] = 0.f; cnt_in[s] = 0.f;
                    int j = atomicAdd(&ctrl[4], 1);
                    if (j < CAP_NL1) NL1[j] = s;
                }
            }
        }
    }
}

// sweep: dst-bit in B1 -> collect L1, set B0, lazy-zero cnt_out.
// Prologue (a) seeds B0 |= B1|B2 (B0 ends as UNION; first-set double-zero is
// idempotent), (b) zeroes agg1 rows (NL1 is final at this boundary).
__global__ __launch_bounds__(256) void k_scan1(
        const int* __restrict__ src, const int* __restrict__ dst,
        const unsigned* __restrict__ B1s, const unsigned* __restrict__ B2,
        unsigned* B0, float* cnt_out, float* bufB,
        const int* __restrict__ NL1, int* L1, int* ctrl) {
    int t = blockIdx.x * blockDim.x + threadIdx.x;
    for (int i = t; i < BMW; i += NBS * 256) {
        unsigned u = B1s[i] | B2[i];
        if (u) atomicOr(&B0[i], u);
    }
    {   // zero agg1 rows (NL1) in bufB
        int n1 = min(ctrl[4], CAP_NL1);
        float4 zz = make_float4(0.f, 0.f, 0.f, 0.f);
        for (int i = t; i < n1 * 16; i += NBS * 256) {
            int v = NL1[i >> 4], c = (i & 15) * 4;
            *(float4*)&bufB[v * HD + c] = zz;
        }
    }
    if (t >= HALF4) return;
    int4 a = ((const int4*)dst)[t];
    int4 b = ((const int4*)dst)[t + HALF4];
#pragma unroll
    for (int h = 0; h < 2; ++h) {
        int4 d4 = h ? b : a;
        int base = (h ? (t + HALF4) : t) * 4;
#pragma unroll
        for (int k = 0; k < 4; ++k) {
            int d = (k == 0) ? d4.x : (k == 1) ? d4.y : (k == 2) ? d4.z : d4.w;
            if ((B1s[d >> 5] >> (d & 31)) & 1u) {
                int e = base + k, s = src[e];
                int idx = atomicAdd(&ctrl[2], 1);
                if (idx < CAP_L1) L1[idx] = e;
                unsigned m = 1u << (s & 31);
                unsigned old = atomicOr(&B0[s >> 5], m);
                if (!(old & m)) cnt_out[s] = 0.f;
            }
        }
    }
}

// fused: [0,NBS) out-deg sweep over union B0 | [NBS,+32) deduped in-deg
__global__ __launch_bounds__(256) void k_mid(
        const int* __restrict__ src, const int* __restrict__ dst,
        const unsigned* __restrict__ B0, const unsigned* __restrict__ B1,
        const unsigned* __restrict__ B2,
        float* cnt_out, float* cnt_in,
        const int* __restrict__ L3, const int* __restrict__ L2,
        const int* __restrict__ L1, const int* __restrict__ ctrl) {
    int blk = blockIdx.x, tid = threadIdx.x;
    if (blk < NBS) {
        int t = blk * 256 + tid;
        if (t >= HALF4) return;
        int4 a = ((const int4*)src)[t];
        int4 b = ((const int4*)src)[t + HALF4];
#pragma unroll
        for (int h = 0; h < 2; ++h) {
            int4 s4 = h ? b : a;
#pragma unroll
            for (int k = 0; k < 4; ++k) {
                int s = (k == 0) ? s4.x : (k == 1) ? s4.y : (k == 2) ? s4.z : s4.w;
                if ((B0[s >> 5] >> (s & 31)) & 1u) atomicAdd(&cnt_out[s], 1.0f);
            }
        }
    } else {
        int e3 = min(ctrl[0], CAP_L3), e2 = min(ctrl[1], CAP_L2), e1 = min(ctrl[2], CAP_L1);
        for (int t = (blk - NBS) * 256 + tid; t < e1 + e2 + e3; t += 32 * 256) {
            int e, which;
            if (t < e1)            { e = L1[t];           which = 1; }
            else if (t < e1 + e2)  { e = L2[t - e1];      which = 2; }
            else                   { e = L3[t - e1 - e2]; which = 3; }
            int d = dst[e];
            bool inB1 = (B1[d >> 5] >> (d & 31)) & 1u;
            bool count;
            if (which == 1)      count = true;
            else if (which == 2) count = !inB1;
            else                 count = !inB1 && !((B2[d >> 5] >> (d & 31)) & 1u);
            if (count) atomicAdd(&cnt_in[d], 1.0f);
        }
    }
}

// scatter1: agg1[d] += w0(s) * zt[z[s]]  (x0 fused, wave per edge)
__global__ __launch_bounds__(256) void k_scatter1(
        const int* __restrict__ L1, const int* __restrict__ ctrl,
        const int* __restrict__ src, const int* __restrict__ dst,
        const int* __restrict__ z, const float* __restrict__ zt,
        const float* __restrict__ cnt_out, float* bufB) {
    int e1 = min(ctrl[2], CAP_L1);
    int gtid = blockIdx.x * blockDim.x + threadIdx.x;
    int gw = gtid >> 6, lane = gtid & 63;
    int nw = (gridDim.x * blockDim.x) >> 6;
    for (int r = gw; r < e1; r += nw) {
        int e = L1[r], s = src[e], d = dst[e];
        float w0 = 1.0f / sqrtf(fmaxf(cnt_out[s], 1.0f));
        atomicAdd(&bufB[d * HD + lane], w0 * zt[z[s] * HD + lane]);
    }
}

// one block, 1024 threads: gemm1, scatter2(LDS agg2), gemm2, scatter3, gemm3,
// MLP. All GEMMs use wave-private LDS row staging: the acc chain is pure FMA
// (256 cy/row) instead of a 64-deep ds_bpermute chain (~3-4K cy/row).
// Accumulation order (i=0..63 from bias) identical to prior rounds.
__global__ __launch_bounds__(1024) void k_last(
        const int* __restrict__ src, const int* __restrict__ dst,
        const int* __restrict__ pair,
        const float* __restrict__ W1, const float* __restrict__ b1,
        const float* __restrict__ W2, const float* __restrict__ b2,
        const float* __restrict__ W3, const float* __restrict__ b3,
        const float* __restrict__ l1w, const float* __restrict__ l1b,
        const float* __restrict__ l2w, const float* __restrict__ l2b,
        float* out, float* bufB,
        const float* __restrict__ cnt_out, const float* __restrict__ cnt_in,
        const int* __restrict__ L3, const int* __restrict__ L2,
        const int* __restrict__ NL2, const int* __restrict__ NL1,
        const int* __restrict__ ctrl) {
    __shared__ float wbuf[HD * HD];          // 16 KB staged weights
    __shared__ float x2agg[S_N2CAP * HD];    // 32 KB agg2/x2 slots
    __shared__ float arow[16][HD];           // 4 KB wave-private row buffers
    __shared__ int   s_nl2[S_N2CAP];
    __shared__ float xs[2 * HD], xf[2 * HD];
    __shared__ int   cnts[8];
    const int tid = threadIdx.x;
    const int wv = tid >> 6, ln = tid & 63;  // 16 waves
    const int p0 = pair[0], p1 = pair[1];

    if (tid < 5) cnts[tid] = ctrl[tid];
    __syncthreads();
    const int e3 = min(cnts[0], CAP_L3), e2 = min(cnts[1], CAP_L2);
    const int n2 = min(cnts[3], S_N2CAP), n1 = min(cnts[4], CAP_NL1);

    for (int i = tid; i < HD * HD; i += 1024) wbuf[i] = W1[i];
    for (int i = tid; i < S_N2CAP * HD; i += 1024) x2agg[i] = 0.0f;
    if (tid < n2) s_nl2[tid] = NL2[tid];
    if (tid < 2 * HD) xs[tid] = 0.0f;
    __syncthreads();

    // gemm1: x1 = relu((agg1*nin) @ W1 + b1), in-place in bufB
    {
        float wb = b1[ln];
        for (int r = wv; r < n1; r += 16) {
            int v = NL1[r];
            float nin = 1.0f / sqrtf(fmaxf(cnt_in[v], 1.0f));
            arow[wv][ln] = bufB[v * HD + ln] * nin;   // wave-coherent LDS scratch
            float acc = wb;
#pragma unroll
            for (int i = 0; i < HD; ++i)
                acc += arow[wv][i] * wbuf[i * HD + ln];
            bufB[v * HD + ln] = fmaxf(acc, 0.0f);
        }
    }
    __syncthreads();

    // scatter2: agg2[slot(d)] += w0(s) * x1[s], wave per edge
    for (int r = wv; r < e2; r += 16) {
        int e = L2[r], s = src[e], d = dst[e];
        float w0 = 1.0f / sqrtf(fmaxf(cnt_out[s], 1.0f));
        int slot = 0;
        for (int j = 0; j < n2; ++j) if (s_nl2[j] == d) { slot = j; break; }
        atomicAdd(&x2agg[slot * HD + ln], w0 * bufB[s * HD + ln]);
    }
    __syncthreads();
    for (int i = tid; i < HD * HD; i += 1024) wbuf[i] = W2[i];
    __syncthreads();

    // gemm2 in LDS: x2 = relu((agg2*nin) @ W2 + b2)
    {
        float wb = b2[ln];
        for (int r = wv; r < n2; r += 16) {
            int v = s_nl2[r];
            float nin = 1.0f / sqrtf(fmaxf(cnt_in[v], 1.0f));
            arow[wv][ln] = x2agg[r * HD + ln] * nin;
            float acc = wb;
#pragma unroll
            for (int i = 0; i < HD; ++i)
                acc += arow[wv][i] * wbuf[i * HD + ln];
            x2agg[r * HD + ln] = fmaxf(acc, 0.0f);
        }
    }
    __syncthreads();

    // scatter3: xs rows {p0,p1} += w0(s) * x2[slot(s)]
    for (int r = wv; r < e3; r += 16) {
        int e = L3[r], s = src[e], d = dst[e];
        float w0 = 1.0f / sqrtf(fmaxf(cnt_out[s], 1.0f));
        int slot = 0;
        for (int j = 0; j < n2; ++j) if (s_nl2[j] == s) { slot = j; break; }
        float c = w0 * x2agg[slot * HD + ln];
        if (d == p0)             atomicAdd(&xs[ln], c);
        if (d == p1 && p1 != p0) atomicAdd(&xs[HD + ln], c);
    }
    __syncthreads();
    for (int i = tid; i < HD * HD; i += 1024) wbuf[i] = W3[i];
    __syncthreads();

    // gemm3 (no relu) on the two pair rows
    if (tid < 128) {
        int pv = wv ? p1 : p0;
        int rs = (wv && p1 != p0) ? 1 : 0;       // p0==p1: both use row 0
        float nin = 1.0f / sqrtf(fmaxf(cnt_in[pv], 1.0f));
        arow[wv][ln] = xs[rs * HD + ln] * nin;
        float acc = b3[ln];
#pragma unroll
        for (int i = 0; i < HD; ++i)
            acc += arow[wv][i] * wbuf[i * HD + ln];
        xf[wv * HD + ln] = acc;
    }
    __syncthreads();
    for (int i = tid; i < HD * HD; i += 1024) wbuf[i] = l1w[i];
    __syncthreads();

    // final MLP
    if (tid < 64) {
        arow[0][tid] = xf[tid] * xf[HD + tid];   // h
        float t2 = l1b[tid];
#pragma unroll
        for (int i = 0; i < HD; ++i)
            t2 += arow[0][i] * wbuf[i * HD + tid];
        t2 = fmaxf(t2, 0.0f);
        float val = t2 * l2w[tid];
#pragma unroll
        for (int off = 32; off; off >>= 1)
            val += __shfl_down(val, off, 64);
        if (tid == 0) out[0] = val + l2b[0];
    }
}

extern "C" void kernel_launch(void* const* d_in, const int* in_sizes, int n_in,
                              void* d_out, int out_size, void* d_ws, size_t ws_size,
                              hipStream_t stream) {
    const int*   z    = (const int*)d_in[0];
    const int*   src  = (const int*)d_in[1];
    const int*   dst  = (const int*)d_in[2];
    const int*   pair = (const int*)d_in[3];
    const float* zt   = (const float*)d_in[4];
    const float* W1   = (const float*)d_in[5];
    const float* b1   = (const float*)d_in[6];
    const float* W2   = (const float*)d_in[7];
    const float* b2   = (const float*)d_in[8];
    const float* W3   = (const float*)d_in[9];
    const float* b3   = (const float*)d_in[10];
    const float* l1w  = (const float*)d_in[11];
    const float* l1b  = (const float*)d_in[12];
    const float* l2w  = (const float*)d_in[13];
    const float* l2b  = (const float*)d_in[14];
    float* out = (float*)d_out;

    char* w = (char*)d_ws;
    auto alloc = [&](size_t bytes) {
        char* p = w;
        w += (bytes + 255) & ~(size_t)255;
        return p;
    };
    float*    bufB    = (float*)alloc((size_t)NN * HD * 4);
    float*    cnt_out = (float*)alloc((size_t)NN * 4);
    float*    cnt_in  = (float*)alloc((size_t)NN * 4);
    unsigned* B0      = (unsigned*)alloc((size_t)BMW * 4);
    unsigned* B1      = (unsigned*)alloc((size_t)BMW * 4);
    unsigned* B2      = (unsigned*)alloc((size_t)BMW * 4);
    int*      L3      = (int*)alloc((size_t)CAP_L3 * 4);
    int*      L2      = (int*)alloc((size_t)CAP_L2 * 4);
    int*      L1      = (int*)alloc((size_t)CAP_L1 * 4);
    int*      NL2     = (int*)alloc((size_t)CAP_NL2 * 4);
    int*      NL1     = (int*)alloc((size_t)CAP_NL1 * 4);
    int*      ctrl    = (int*)alloc(256);

    dim3 b(256);

    k_init<<<40, b, 0, stream>>>(B0, B1, B2, ctrl, cnt_in, pair);
    k_scan3<<<NBS, b, 0, stream>>>(src, dst, pair, B2, cnt_out, cnt_in, L3, NL2, ctrl);
    k_scan2<<<NBS, b, 0, stream>>>(src, dst, B2, B1, cnt_out, cnt_in, L2, NL1, ctrl);
    k_scan1<<<NBS, b, 0, stream>>>(src, dst, B1, B2, B0, cnt_out, bufB, NL1, L1, ctrl);
    k_mid<<<NBS + 32, b, 0, stream>>>(src, dst, B0, B1, B2, cnt_out, cnt_in,
                                      L3, L2, L1, ctrl);
    k_scatter1<<<512, b, 0, stream>>>(L1, ctrl, src, dst, z, zt, cnt_out, bufB);
    k_last<<<1, 1024, 0, stream>>>(src, dst, pair, W1, b1, W2, b2, W3, b3,
                                   l1w, l1b, l2w, l2b, out, bufB,
                                   cnt_out, cnt_in, L3, L2, NL2, NL1, ctrl);
}

// Round 11
// 110.703 us; speedup vs baseline: 2.3444x; 1.5849x over previous
//
#include <hip/hip_runtime.h>

#define NN 100000
#define NE 1250000
#define HD 64
#define BMW 3125            // bitmap words = NN/32
#define HALF4 156250        // (NE/4)/2 int4 elements per half
#define NBS 611             // ceil(HALF4/256) sweep blocks

#define CAP_L3   4096
#define CAP_L2   65536
#define CAP_L1   262144
#define CAP_NL2  4096
#define CAP_NL1  65536

#define TBLK 16             // tail blocks
#define TWAVES (TBLK * 16)  // 256 tail waves

// ctrl: 0=cntL3 1=cntL2 2=cntL1 3=cntNL2 4=cntNL1
// B2 = NL2 (in-nbrs of pair), B1 = NL1, B0 = NL0 then UNION (seeded in scan1).
// Cross-kernel visibility via kernel boundaries. Inside k_tail, cross-phase
// mutable data uses agent-scope relaxed atomics + the fence-free gbar
// (validated in R4/R5/R7: absmax 0 each time).

__device__ __forceinline__ float ldg_f(const float* p) {
    return __hip_atomic_load(p, __ATOMIC_RELAXED, __HIP_MEMORY_SCOPE_AGENT);
}
__device__ __forceinline__ void stg_f(float* p, float v) {
    __hip_atomic_store(p, v, __ATOMIC_RELAXED, __HIP_MEMORY_SCOPE_AGENT);
}

__device__ __forceinline__ void gbar(unsigned* cnt16, unsigned target) {
    __syncthreads();     // drains vmcnt: this block's stores reached LLC
    if (threadIdx.x == 0) {
        __hip_atomic_fetch_add(&cnt16[(blockIdx.x & 15u) * 16], 1u,
                               __ATOMIC_RELAXED, __HIP_MEMORY_SCOPE_AGENT);
        long guard = 0;
        for (;;) {
            unsigned s = 0;
#pragma unroll
            for (int i = 0; i < 16; ++i)
                s += __hip_atomic_load(&cnt16[i * 16], __ATOMIC_RELAXED,
                                       __HIP_MEMORY_SCOPE_AGENT);
            if (s >= target) break;
            __builtin_amdgcn_s_sleep(1);
            if (++guard > (1L << 22)) break;   // deadlock escape
        }
        asm volatile("" ::: "memory");
    }
    __syncthreads();
}

// sweep: edges into {pair}; mark srcs in B2, append NL2, lazy-zero counters
__global__ __launch_bounds__(256) void k_scan3(
        const int* __restrict__ src, const int* __restrict__ dst,
        const int* __restrict__ pair, unsigned* B2,
        float* cnt_out, float* cnt_in, int* L3, int* NL2, int* ctrl) {
    int t = blockIdx.x * blockDim.x + threadIdx.x;
    int p0 = pair[0], p1 = pair[1];
    if (blockIdx.x == 0 && threadIdx.x == 0) {   // pair in-deg lazy zero
        cnt_in[p0] = 0.f; cnt_in[p1] = 0.f;      // benign 0-write races only
    }
    if (t >= HALF4) return;
    int4 a = ((const int4*)dst)[t];              // two independent loads
    int4 b = ((const int4*)dst)[t + HALF4];
#pragma unroll
    for (int h = 0; h < 2; ++h) {
        int4 d4 = h ? b : a;
        int base = (h ? (t + HALF4) : t) * 4;
#pragma unroll
        for (int k = 0; k < 4; ++k) {
            int d = (k == 0) ? d4.x : (k == 1) ? d4.y : (k == 2) ? d4.z : d4.w;
            if (d == p0 || d == p1) {
                int e = base + k, s = src[e];
                int idx = atomicAdd(&ctrl[0], 1);
                if (idx < CAP_L3) L3[idx] = e;
                unsigned m = 1u << (s & 31);
                unsigned old = atomicOr(&B2[s >> 5], m);
                if (!(old & m)) {
                    cnt_out[s] = 0.f; cnt_in[s] = 0.f;
                    int j = atomicAdd(&ctrl[3], 1);
                    if (j < CAP_NL2) NL2[j] = s;
                }
            }
        }
    }
}

// sweep: dst-bit in B2 -> collect L2, set B1/NL1, lazy-zero
__global__ __launch_bounds__(256) void k_scan2(
        const int* __restrict__ src, const int* __restrict__ dst,
        const unsigned* __restrict__ B2, unsigned* B1,
        float* cnt_out, float* cnt_in, int* L2, int* NL1, int* ctrl) {
    int t = blockIdx.x * blockDim.x + threadIdx.x;
    if (t >= HALF4) return;
    int4 a = ((const int4*)dst)[t];
    int4 b = ((const int4*)dst)[t + HALF4];
#pragma unroll
    for (int h = 0; h < 2; ++h) {
        int4 d4 = h ? b : a;
        int base = (h ? (t + HALF4) : t) * 4;
#pragma unroll
        for (int k = 0; k < 4; ++k) {
            int d = (k == 0) ? d4.x : (k == 1) ? d4.y : (k == 2) ? d4.z : d4.w;
            if ((B2[d >> 5] >> (d & 31)) & 1u) {
                int e = base + k, s = src[e];
                int idx = atomicAdd(&ctrl[1], 1);
                if (idx < CAP_L2) L2[idx] = e;
                unsigned m = 1u << (s & 31);
                unsigned old = atomicOr(&B1[s >> 5], m);
                if (!(old & m)) {
                    cnt_out[s] = 0.f; cnt_in[s] = 0.f;
                    int j = atomicAdd(&ctrl[4], 1);
                    if (j < CAP_NL1) NL1[j] = s;
                }
            }
        }
    }
}

// sweep: dst-bit in B1 -> collect L1, set B0, lazy-zero cnt_out.
// Prologue (a) seeds B0 |= B1|B2 (B0 ends as UNION; double-zero idempotent),
// (b) zeroes agg1 rows (NL1 final at this boundary).
__global__ __launch_bounds__(256) void k_scan1(
        const int* __restrict__ src, const int* __restrict__ dst,
        const unsigned* __restrict__ B1s, const unsigned* __restrict__ B2,
        unsigned* B0, float* cnt_out, float* bufB,
        const int* __restrict__ NL1, int* L1, int* ctrl) {
    int t = blockIdx.x * blockDim.x + threadIdx.x;
    for (int i = t; i < BMW; i += NBS * 256) {
        unsigned u = B1s[i] | B2[i];
        if (u) atomicOr(&B0[i], u);
    }
    {   // zero agg1 rows (NL1) in bufB
        int n1 = min(ctrl[4], CAP_NL1);
        float4 zz = make_float4(0.f, 0.f, 0.f, 0.f);
        for (int i = t; i < n1 * 16; i += NBS * 256) {
            int v = NL1[i >> 4], c = (i & 15) * 4;
            *(float4*)&bufB[v * HD + c] = zz;
        }
    }
    if (t >= HALF4) return;
    int4 a = ((const int4*)dst)[t];
    int4 b = ((const int4*)dst)[t + HALF4];
#pragma unroll
    for (int h = 0; h < 2; ++h) {
        int4 d4 = h ? b : a;
        int base = (h ? (t + HALF4) : t) * 4;
#pragma unroll
        for (int k = 0; k < 4; ++k) {
            int d = (k == 0) ? d4.x : (k == 1) ? d4.y : (k == 2) ? d4.z : d4.w;
            if ((B1s[d >> 5] >> (d & 31)) & 1u) {
                int e = base + k, s = src[e];
                int idx = atomicAdd(&ctrl[2], 1);
                if (idx < CAP_L1) L1[idx] = e;
                unsigned m = 1u << (s & 31);
                unsigned old = atomicOr(&B0[s >> 5], m);
                if (!(old & m)) cnt_out[s] = 0.f;
            }
        }
    }
}

// fused: [0,NBS) out-deg sweep over union B0 | [NBS,+32) deduped in-deg
__global__ __launch_bounds__(256) void k_mid(
        const int* __restrict__ src, const int* __restrict__ dst,
        const unsigned* __restrict__ B0, const unsigned* __restrict__ B1,
        const unsigned* __restrict__ B2,
        float* cnt_out, float* cnt_in,
        const int* __restrict__ L3, const int* __restrict__ L2,
        const int* __restrict__ L1, const int* __restrict__ ctrl) {
    int blk = blockIdx.x, tid = threadIdx.x;
    if (blk < NBS) {
        int t = blk * 256 + tid;
        if (t >= HALF4) return;
        int4 a = ((const int4*)src)[t];
        int4 b = ((const int4*)src)[t + HALF4];
#pragma unroll
        for (int h = 0; h < 2; ++h) {
            int4 s4 = h ? b : a;
#pragma unroll
            for (int k = 0; k < 4; ++k) {
                int s = (k == 0) ? s4.x : (k == 1) ? s4.y : (k == 2) ? s4.z : s4.w;
                if ((B0[s >> 5] >> (s & 31)) & 1u) atomicAdd(&cnt_out[s], 1.0f);
            }
        }
    } else {
        int e3 = min(ctrl[0], CAP_L3), e2 = min(ctrl[1], CAP_L2), e1 = min(ctrl[2], CAP_L1);
        for (int t = (blk - NBS) * 256 + tid; t < e1 + e2 + e3; t += 32 * 256) {
            int e, which;
            if (t < e1)            { e = L1[t];           which = 1; }
            else if (t < e1 + e2)  { e = L2[t - e1];      which = 2; }
            else                   { e = L3[t - e1 - e2]; which = 3; }
            int d = dst[e];
            bool inB1 = (B1[d >> 5] >> (d & 31)) & 1u;
            bool count;
            if (which == 1)      count = true;
            else if (which == 2) count = !inB1;
            else                 count = !inB1 && !((B2[d >> 5] >> (d & 31)) & 1u);
            if (count) atomicAdd(&cnt_in[d], 1.0f);
        }
    }
}

// scatter1: agg1[d] += w0(s) * zt[z[s]]  (x0 fused, wave per edge)
__global__ __launch_bounds__(256) void k_scatter1(
        const int* __restrict__ L1, const int* __restrict__ ctrl,
        const int* __restrict__ src, const int* __restrict__ dst,
        const int* __restrict__ z, const float* __restrict__ zt,
        const float* __restrict__ cnt_out, float* bufB) {
    int e1 = min(ctrl[2], CAP_L1);
    int gtid = blockIdx.x * blockDim.x + threadIdx.x;
    int gw = gtid >> 6, lane = gtid & 63;
    int nw = (gridDim.x * blockDim.x) >> 6;
    for (int r = gw; r < e1; r += nw) {
        int e = L1[r], s = src[e], d = dst[e];
        float w0 = 1.0f / sqrtf(fmaxf(cnt_out[s], 1.0f));
        atomicAdd(&bufB[d * HD + lane], w0 * zt[z[s] * HD + lane]);
    }
}

// 16-block tail with internal grid barriers: gemm1(+zero agg2/x3) | scatter2 |
// gemm2 | scatter3 | block0: gemm3+MLP. 256 waves -> 1-2 items/wave/phase.
__global__ __launch_bounds__(1024) void k_tail(
        const int* __restrict__ src, const int* __restrict__ dst,
        const int* __restrict__ pair,
        const float* __restrict__ W1, const float* __restrict__ b1,
        const float* __restrict__ W2, const float* __restrict__ b2,
        const float* __restrict__ W3, const float* __restrict__ b3,
        const float* __restrict__ l1w, const float* __restrict__ l1b,
        const float* __restrict__ l2w, const float* __restrict__ l2b,
        float* out, float* bufA, float* bufB, float* x3buf,
        const float* __restrict__ cnt_out, const float* __restrict__ cnt_in,
        const int* __restrict__ L3, const int* __restrict__ L2,
        const int* __restrict__ NL2, const int* __restrict__ NL1,
        const int* __restrict__ ctrl, unsigned* cnt16) {
    __shared__ float arow[16][HD];   // wave-private row staging (R9-proven)
    __shared__ float xls[2 * HD];
    __shared__ int cnts[8];
    const int tid = threadIdx.x, blk = blockIdx.x;
    const int wv = tid >> 6, ln = tid & 63;
    const int gw = blk * 16 + wv;                 // 0..255 global wave
    const int p0 = pair[0], p1 = pair[1];

    if (tid < 5) cnts[tid] = ctrl[tid];
    __syncthreads();
    const int e3 = min(cnts[0], CAP_L3), e2 = min(cnts[1], CAP_L2);
    const int n2 = min(cnts[3], CAP_NL2), n1 = min(cnts[4], CAP_NL1);

    // phase 1: gemm1 (x1 = relu((agg1*nin)@W1+b1)) + zero agg2 rows + x3buf
    for (int r = gw; r < n1 + n2; r += TWAVES) {
        if (r < n1) {
            int v = NL1[r];
            float nin = 1.0f / sqrtf(fmaxf(cnt_in[v], 1.0f));
            arow[wv][ln] = bufB[v * HD + ln] * nin;
            float acc = b1[ln];
#pragma unroll
            for (int i = 0; i < HD; ++i)
                acc += arow[wv][i] * W1[i * HD + ln];
            stg_f(&bufB[v * HD + ln], fmaxf(acc, 0.0f));
        } else {
            stg_f(&bufA[NL2[r - n1] * HD + ln], 0.0f);
        }
    }
    if (blk == 0 && tid < 2 * HD) stg_f(&x3buf[tid], 0.0f);
    gbar(cnt16, 1u * TBLK);

    // phase 2: scatter2 — agg2[d] += w0(s) * x1[s]
    for (int r = gw; r < e2; r += TWAVES) {
        int e = L2[r], s = src[e], d = dst[e];
        float w0 = 1.0f / sqrtf(fmaxf(cnt_out[s], 1.0f));
        atomicAdd(&bufA[d * HD + ln], w0 * ldg_f(&bufB[s * HD + ln]));
    }
    gbar(cnt16, 2u * TBLK);

    // phase 3: gemm2 — x2 = relu((agg2*nin)@W2+b2), in-place in bufA
    for (int r = gw; r < n2; r += TWAVES) {
        int v = NL2[r];
        float nin = 1.0f / sqrtf(fmaxf(cnt_in[v], 1.0f));
        arow[wv][ln] = ldg_f(&bufA[v * HD + ln]) * nin;
        float acc = b2[ln];
#pragma unroll
        for (int i = 0; i < HD; ++i)
            acc += arow[wv][i] * W2[i * HD + ln];
        stg_f(&bufA[v * HD + ln], fmaxf(acc, 0.0f));
    }
    gbar(cnt16, 3u * TBLK);

    // phase 4: scatter3 — x3buf rows {p0,p1} += w0(s) * x2[s]
    for (int r = gw; r < e3; r += TWAVES) {
        int e = L3[r], s = src[e], d = dst[e];
        float w0 = 1.0f / sqrtf(fmaxf(cnt_out[s], 1.0f));
        float c = w0 * ldg_f(&bufA[s * HD + ln]);
        if (d == p0)             atomicAdd(&x3buf[ln], c);
        if (d == p1 && p1 != p0) atomicAdd(&x3buf[HD + ln], c);
    }
    gbar(cnt16, 4u * TBLK);

    // phase 5 (block 0): gemm3 (no relu) + final MLP
    if (blk != 0) return;
    if (tid < 128) {
        int pv = wv ? p1 : p0;
        int rs = (wv && p1 != p0) ? 1 : 0;       // p0==p1: both use row 0
        float nin = 1.0f / sqrtf(fmaxf(cnt_in[pv], 1.0f));
        arow[wv][ln] = ldg_f(&x3buf[rs * HD + ln]) * nin;
        float acc = b3[ln];
#pragma unroll
        for (int i = 0; i < HD; ++i)
            acc += arow[wv][i] * W3[i * HD + ln];
        xls[wv * HD + ln] = acc;
    }
    __syncthreads();
    if (tid < 64) {
        arow[0][tid] = xls[tid] * xls[HD + tid];   // h
        float t2 = l1b[tid];
#pragma unroll
        for (int i = 0; i < HD; ++i)
            t2 += arow[0][i] * l1w[i * HD + tid];
        t2 = fmaxf(t2, 0.0f);
        float val = t2 * l2w[tid];
#pragma unroll
        for (int off = 32; off; off >>= 1)
            val += __shfl_down(val, off, 64);
        if (tid == 0) out[0] = val + l2b[0];
    }
}

extern "C" void kernel_launch(void* const* d_in, const int* in_sizes, int n_in,
                              void* d_out, int out_size, void* d_ws, size_t ws_size,
                              hipStream_t stream) {
    const int*   z    = (const int*)d_in[0];
    const int*   src  = (const int*)d_in[1];
    const int*   dst  = (const int*)d_in[2];
    const int*   pair = (const int*)d_in[3];
    const float* zt   = (const float*)d_in[4];
    const float* W1   = (const float*)d_in[5];
    const float* b1   = (const float*)d_in[6];
    const float* W2   = (const float*)d_in[7];
    const float* b2   = (const float*)d_in[8];
    const float* W3   = (const float*)d_in[9];
    const float* b3   = (const float*)d_in[10];
    const float* l1w  = (const float*)d_in[11];
    const float* l1b  = (const float*)d_in[12];
    const float* l2w  = (const float*)d_in[13];
    const float* l2b  = (const float*)d_in[14];
    float* out = (float*)d_out;

    char* w = (char*)d_ws;
    auto alloc = [&](size_t bytes) {
        char* p = w;
        w += (bytes + 255) & ~(size_t)255;
        return p;
    };
    // contiguous memset region: [cnt16 | ctrl | B0 | B1 | B2]
    unsigned* cnt16   = (unsigned*)alloc(1024);
    int*      ctrl    = (int*)alloc(256);
    unsigned* B0      = (unsigned*)alloc((size_t)BMW * 4);
    unsigned* B1      = (unsigned*)alloc((size_t)BMW * 4);
    unsigned* B2      = (unsigned*)alloc((size_t)BMW * 4);
    char*     zend    = w;
    float*    bufA    = (float*)alloc((size_t)NN * HD * 4);
    float*    bufB    = (float*)alloc((size_t)NN * HD * 4);
    float*    cnt_out = (float*)alloc((size_t)NN * 4);
    float*    cnt_in  = (float*)alloc((size_t)NN * 4);
    int*      L3      = (int*)alloc((size_t)CAP_L3 * 4);
    int*      L2      = (int*)alloc((size_t)CAP_L2 * 4);
    int*      L1      = (int*)alloc((size_t)CAP_L1 * 4);
    int*      NL2     = (int*)alloc((size_t)CAP_NL2 * 4);
    int*      NL1     = (int*)alloc((size_t)CAP_NL1 * 4);
    float*    x3buf   = (float*)alloc(2 * HD * 4);

    dim3 b(256);

    hipMemsetAsync(cnt16, 0, (size_t)(zend - (char*)cnt16), stream);
    k_scan3<<<NBS, b, 0, stream>>>(src, dst, pair, B2, cnt_out, cnt_in, L3, NL2, ctrl);
    k_scan2<<<NBS, b, 0, stream>>>(src, dst, B2, B1, cnt_out, cnt_in, L2, NL1, ctrl);
    k_scan1<<<NBS, b, 0, stream>>>(src, dst, B1, B2, B0, cnt_out, bufB, NL1, L1, ctrl);
    k_mid<<<NBS + 32, b, 0, stream>>>(src, dst, B0, B1, B2, cnt_out, cnt_in,
                                      L3, L2, L1, ctrl);
    k_scatter1<<<512, b, 0, stream>>>(L1, ctrl, src, dst, z, zt, cnt_out, bufB);
    k_tail<<<TBLK, 1024, 0, stream>>>(src, dst, pair, W1, b1, W2, b2, W3, b3,
                                      l1w, l1b, l2w, l2b, out, bufA, bufB, x3buf,
                                      cnt_out, cnt_in, L3, L2, NL2, NL1,
                                      ctrl, cnt16);
}